// Round 7
// baseline (297.796 us; speedup 1.0000x reference)
//
#include <hip/hip_runtime.h>

#define T_PTS 8192
#define D_DIM 128
#define C_OUT 16
#define NSPLIT 8
#define JSPAN (T_PTS / NSPLIT) /* 1024 */
#define NJT (JSPAN / 64)       /* 16 */
#define LSTR 132               /* fp32 LDS stride for y part */
#define NC (NSPLIT * 4)        /* 32 candidates per row */
#define MSTR 65                /* merge scratch row stride */
#define RS_BLOCKS (T_PTS / 2)  /* rescore blocks (2 rows each) in mid_kernel */
#define CSTR 133               /* rescore staging stride in floats (conflict-free: 133%32=5) */

typedef _Float16 half8 __attribute__((ext_vector_type(8)));
typedef __attribute__((ext_vector_type(4))) float f32x4;
typedef unsigned short ushort_t;
typedef unsigned int uint_t;

// ---------------------------------------------------------------- prep: fp32->fp16 + rowwise sumsq
__global__ void prep_kernel(const float* __restrict__ X, _Float16* __restrict__ Xh,
                            float* __restrict__ sq) {
    const int tid = threadIdx.x;
    const int row = blockIdx.x * 16 + (tid >> 4);
    const int c8 = (tid & 15) * 8;
    const float4* p = (const float4*)(X + row * D_DIM + c8);
    const float4 a = p[0], b = p[1];
    half8 o;
    o[0] = (_Float16)a.x; o[1] = (_Float16)a.y; o[2] = (_Float16)a.z; o[3] = (_Float16)a.w;
    o[4] = (_Float16)b.x; o[5] = (_Float16)b.y; o[6] = (_Float16)b.z; o[7] = (_Float16)b.w;
    *(half8*)(Xh + row * D_DIM + c8) = o;
    float s = a.x * a.x + a.y * a.y + a.z * a.z + a.w * a.w
            + b.x * b.x + b.y * b.y + b.z * b.z + b.w * b.w;
    s += __shfl_xor(s, 1); s += __shfl_xor(s, 2);
    s += __shfl_xor(s, 4); s += __shfl_xor(s, 8);
    if ((tid & 15) == 0) sq[row] = s;
}

// ---------------------------------------------------------------- MFMA fp16 scores, barrier-free
// fp16 keys are CANDIDATE-RECALL ONLY; final ordering is re-derived in fp32 by mid_kernel
// with the exact accumulation order validated in rounds 1/4/6.
// Keys carry a 6-bit stream-local index in the low mantissa bits (<=64ulp perturbation,
// recall-irrelevant) so selection is pure min/med3 with no index cndmasks.
__launch_bounds__(256, 4)
__global__ void nn_kernel(const _Float16* __restrict__ Xh, const float* __restrict__ sq,
                          ushort_t* __restrict__ cand) {
    __shared__ float mk[64 * MSTR];
    __shared__ int mj[64 * MSTR];

    const int tid = threadIdx.x;
    const int w = tid >> 6;
    const int lane = tid & 63;
    const int quad = lane >> 4;
    const int l15 = lane & 15;
    const int i0 = blockIdx.x * 64;
    const int sp = blockIdx.y;
    const int j0 = sp * JSPAN;

    // B-operand frags (i side), loaded straight from global (coalesced; L2-resident)
    half8 bfrag[4][4];
#pragma unroll
    for (int n = 0; n < 4; ++n)
#pragma unroll
        for (int k = 0; k < 4; ++k)
            bfrag[n][k] = *(const half8*)(Xh + (i0 + n * 16 + l15) * D_DIM + k * 32 + quad * 8);

    float c0[4], c1[4], c2[4], c3[4], sk[4];
#pragma unroll
    for (int n = 0; n < 4; ++n) { c0[n] = c1[n] = c2[n] = c3[n] = sk[n] = 1e30f; }

    int icol[4];
#pragma unroll
    for (int n = 0; n < 4; ++n) icol[n] = i0 + n * 16 + l15;

    const bool blk_excl = (sp == (i0 / JSPAN));
    const int excl_jt = (i0 & (JSPAN - 1)) >> 6;

#pragma unroll 4
    for (int jt = 0; jt < NJT; ++jt) {
        const int jbase = j0 + jt * 64;
        const int jrow = jbase + w * 16 + l15;
        half8 af[4];
#pragma unroll
        for (int k = 0; k < 4; ++k)
            af[k] = *(const half8*)(Xh + jrow * D_DIM + k * 32 + quad * 8);
        const f32x4 sq4 = *(const f32x4*)(sq + jbase + w * 16 + quad * 4);
        const int jg = jbase + w * 16 + quad * 4;  // + r
        const bool excl = blk_excl && (jt == excl_jt);
        const uint_t ib = (uint_t)(jt * 4);

#pragma unroll
        for (int n = 0; n < 4; ++n) {
            f32x4 acc = {0.f, 0.f, 0.f, 0.f};
#pragma unroll
            for (int k = 0; k < 4; ++k)
                acc = __builtin_amdgcn_mfma_f32_16x16x32_f16(af[k], bfrag[n][k], acc, 0, 0, 0);
            float q0 = fmaf(-2.f, acc[0], sq4[0]);
            float q1 = fmaf(-2.f, acc[1], sq4[1]);
            float q2 = fmaf(-2.f, acc[2], sq4[2]);
            float q3 = fmaf(-2.f, acc[3], sq4[3]);
            if (excl) {  // wave-uniform branch; self-exclusion BEFORE packing/selection
                if (jg + 0 == icol[n]) q0 = 1e30f;
                if (jg + 1 == icol[n]) q1 = 1e30f;
                if (jg + 2 == icol[n]) q2 = 1e30f;
                if (jg + 3 == icol[n]) q3 = 1e30f;
            }
            const float p0 = __uint_as_float((__float_as_uint(q0) & 0xFFFFFFC0u) | (ib + 0));
            const float p1 = __uint_as_float((__float_as_uint(q1) & 0xFFFFFFC0u) | (ib + 1));
            const float p2 = __uint_as_float((__float_as_uint(q2) & 0xFFFFFFC0u) | (ib + 2));
            const float p3 = __uint_as_float((__float_as_uint(q3) & 0xFFFFFFC0u) | (ib + 3));
            // quad top-2 via pure min/max network (indices ride in the low bits)
            const float min01 = fminf(p0, p1), max01 = fmaxf(p0, p1);
            const float min23 = fminf(p2, p3), max23 = fmaxf(p2, p3);
            const float kmin = fminf(min01, min23);
            const float ksec = fminf(fmaxf(min01, min23), fminf(max01, max23));
            // quad-min -> sorted top-4 chain (med3)
            c3[n] = __builtin_amdgcn_fmed3f(c2[n], c3[n], kmin);
            c2[n] = __builtin_amdgcn_fmed3f(c1[n], c2[n], kmin);
            c1[n] = __builtin_amdgcn_fmed3f(c0[n], c1[n], kmin);
            c0[n] = fminf(c0[n], kmin);
            // quad-second -> side top-1
            sk[n] = fminf(sk[n], ksec);
        }
    }

    // fold side value into each chain (once per stream per n)
#pragma unroll
    for (int n = 0; n < 4; ++n) {
        const float v = sk[n];
        c3[n] = __builtin_amdgcn_fmed3f(c2[n], c3[n], v);
        c2[n] = __builtin_amdgcn_fmed3f(c1[n], c2[n], v);
        c1[n] = __builtin_amdgcn_fmed3f(c0[n], c1[n], v);
        c0[n] = fminf(c0[n], v);
    }

    // decode + write: 16 streams x top-4 -> merge scratch
    const int s = w * 4 + quad;
    const int jdec0 = j0 + w * 16 + quad * 4;  // + (p>>2)*64 + (p&3)
#pragma unroll
    for (int n = 0; n < 4; ++n) {
        const int il = n * 16 + l15;
        const int base = il * MSTR + s * 4;
        float cc[4] = {c0[n], c1[n], c2[n], c3[n]};
#pragma unroll
        for (int e = 0; e < 4; ++e) {
            const uint_t p = __float_as_uint(cc[e]) & 63u;
            mk[base + e] = cc[e];
            mj[base + e] = jdec0 + (int)(p >> 2) * 64 + (int)(p & 3);
        }
    }
    __syncthreads();
    if (tid < 64) {
        float a0 = 1e30f, a1 = 1e30f, a2 = 1e30f, a3 = 1e30f;
        int b0 = 0, b1 = 0, b2 = 0, b3 = 0;
        for (int e = 0; e < 64; ++e) {
            float k = mk[tid * MSTR + e];
            int j = mj[tid * MSTR + e];
            bool l0 = k < a0, l1 = k < a1, l2 = k < a2, l3 = k < a3;
            a3 = l2 ? a2 : (l3 ? k : a3); b3 = l2 ? b2 : (l3 ? j : b3);
            a2 = l1 ? a1 : (l2 ? k : a2); b2 = l1 ? b1 : (l2 ? j : b2);
            a1 = l0 ? a0 : (l1 ? k : a1); b1 = l0 ? b0 : (l1 ? j : b1);
            a0 = l0 ? k : a0;             b0 = l0 ? j : b0;
        }
        const int gi = i0 + tid;
        ushort_t* c = cand + (sp * T_PTS + gi) * 4;
        c[0] = (ushort_t)b0; c[1] = (ushort_t)b1; c[2] = (ushort_t)b2; c[3] = (ushort_t)b3;
    }
}

// ---------------------------------------------------------------- mid: LDS-staged rescore + Y=XW+b
// CRITICAL: the rescore dot MUST stay a per-thread sequential fma chain
// (`ssum += a.x*b.x;` x4, loop over q) — this accumulation order matched the
// reference in rounds 1/4/6. LDS staging copies bits exactly; values unchanged.
__global__ void mid_kernel(const float* __restrict__ X, const float* __restrict__ sq,
                           const ushort_t* __restrict__ cand, int* __restrict__ nbrs,
                           const float* __restrict__ W, const float* __restrict__ b,
                           float* __restrict__ Y, float* __restrict__ out) {
    __shared__ float Cs[64 * CSTR];   // 64 candidate rows (34048 B), also aliases y-part usage below
    __shared__ int jrowLds[64];
    __shared__ float keys[2][NC];
    __shared__ int idxs[2][NC];
    const int tid = threadIdx.x;

    if (blockIdx.x < RS_BLOCKS) {
        const int ibase = blockIdx.x * 2;
        // candidate indices for the 2 rows (64 total)
        if (tid < 64) {
            const int ii = tid >> 5, t = tid & 31;
            const int spc = t >> 2, e = t & 3;
            jrowLds[tid] = (int)cand[(spc * T_PTS + (ibase + ii)) * 4 + e];
        }
        __syncthreads();
        // stage 64 candidate rows, globally coalesced (32 lanes per 512B row)
#pragma unroll
        for (int it = 0; it < 8; ++it) {
            const int f = tid + it * 256;     // 0..2047
            const int cr = f >> 5, q = f & 31;
            const int j = jrowLds[cr];
            *(float4*)(Cs + cr * CSTR + q * 4) = *(const float4*)(X + j * D_DIM + q * 4);
        }
        __syncthreads();
        if (tid < 64) {
            const int ii = tid >> 5, t = tid & 31;
            const int i = ibase + ii;
            const int j = jrowLds[tid];
            const float4* xi = (const float4*)(X + i * D_DIM);
            const float* xb = Cs + tid * CSTR;
            float ssum = 0.f;
#pragma unroll
            for (int q = 0; q < 32; ++q) {
                const float4 a = xi[q];
                const float4 b2 = *(const float4*)(xb + q * 4);
                ssum += a.x * b2.x; ssum += a.y * b2.y; ssum += a.z * b2.z; ssum += a.w * b2.w;
            }
            float key = sq[j] - 2.f * ssum;
            if (j == i) key = 1e30f;
            keys[ii][t] = key;
            idxs[ii][t] = j;
        }
        __syncthreads();
        if ((tid & 31) == 0 && tid < 64) {
            const int ii = tid >> 5;
            float m0 = 1e30f, m1 = 1e30f;
            int n0 = 0x7fffffff, n1 = 0x7fffffff;
            for (int e = 0; e < NC; ++e) {
                float k = keys[ii][e];
                int j = idxs[ii][e];
                bool lt0 = (k < m0) || (k == m0 && j < n0);
                bool lt1 = (k < m1) || (k == m1 && j < n1);
                if (lt0) { m1 = m0; n1 = n0; m0 = k; n0 = j; }
                else if (lt1) { m1 = k; n1 = j; }
            }
            const int i = ibase + ii;
            nbrs[i * 2 + 0] = n0;
            nbrs[i * 2 + 1] = n1;
        }
    } else {
        // Y = X@W + b, plus logits rows [0,T)
        __shared__ float Ws[D_DIM * C_OUT];
        float* Xs = Cs;  // reuse staging buffer (16*LSTR <= 64*CSTR)
        const int r0 = (blockIdx.x - RS_BLOCKS) * 16;
        const float4* src = (const float4*)(X + r0 * D_DIM);
#pragma unroll
        for (int it = 0; it < 2; ++it) {
            int f = tid + it * 256;  // 0..511
            int row = f >> 5, kq = f & 31;
            *(float4*)(Xs + row * LSTR + kq * 4) = src[row * 32 + kq];
        }
#pragma unroll
        for (int it = 0; it < 2; ++it) {
            int f = tid + it * 256;
            ((float4*)Ws)[f] = ((const float4*)W)[f];
        }
        __syncthreads();
        const int r = tid >> 4, c = tid & 15;
        float s = b[c];
#pragma unroll
        for (int d = 0; d < D_DIM; ++d) s += Xs[r * LSTR + d] * Ws[d * C_OUT + c];
        const int row = r0 + r;
        Y[row * C_OUT + c] = s;
        out[row * C_OUT + c] = s;
    }
}

// ---------------------------------------------------------------- synthetic rows: lerp of Y
__global__ void syn_kernel(const float* __restrict__ Y, const int* __restrict__ nbrs,
                           const int* __restrict__ nn_idx, const float* __restrict__ gaps,
                           float* __restrict__ out) {
    const int idx = blockIdx.x * 256 + threadIdx.x;
    const int m = idx >> 4;
    const int c = idx & 15;
    const int src = m >> 2;       // repeat(arange(T), 4)
    const int sel = nn_idx[m];    // 0 or 1
    const int ch = nbrs[src * 2 + sel];
    const float g = gaps[m];
    const float ys = Y[src * C_OUT + c];
    const float yc = Y[ch * C_OUT + c];
    out[(T_PTS + m) * C_OUT + c] = ys + g * (yc - ys);
}

extern "C" void kernel_launch(void* const* d_in, const int* in_sizes, int n_in,
                              void* d_out, int out_size, void* d_ws, size_t ws_size,
                              hipStream_t stream) {
    const float* X = (const float*)d_in[0];
    const int* nn_idx = (const int*)d_in[1];
    const float* gaps = (const float*)d_in[2];
    const float* W = (const float*)d_in[3];
    const float* b = (const float*)d_in[4];
    float* out = (float*)d_out;

    char* ws = (char*)d_ws;
    _Float16* Xh = (_Float16*)ws;                                  // 2 MB
    float* sq = (float*)(ws + 2097152);                            // 32 KB
    ushort_t* cand = (ushort_t*)(ws + 2097152 + 32768);            // 512 KB
    int* nbrs = (int*)(ws + 2097152 + 32768 + 524288);             // 64 KB
    float* Y = (float*)(ws + 2097152 + 32768 + 524288 + 65536);    // 512 KB

    prep_kernel<<<T_PTS / 16, 256, 0, stream>>>(X, Xh, sq);
    nn_kernel<<<dim3(T_PTS / 64, NSPLIT), 256, 0, stream>>>(Xh, sq, cand);
    mid_kernel<<<RS_BLOCKS + T_PTS / 16, 256, 0, stream>>>(X, sq, cand, nbrs, W, b, Y, out);
    syn_kernel<<<(4 * T_PTS * C_OUT) / 256, 256, 0, stream>>>(Y, nbrs, nn_idx, gaps, out);
}

// Round 8
// 145.557 us; speedup vs baseline: 2.0459x; 2.0459x over previous
//
#include <hip/hip_runtime.h>

#define T_PTS 8192
#define D_DIM 128
#define C_OUT 16
#define NSPLIT 8
#define JSPAN (T_PTS / NSPLIT) /* 1024 */
#define NJT (JSPAN / 64)       /* 16 */
#define LSTR 132               /* fp32 LDS stride for y part */
#define NC (NSPLIT * 4)        /* 32 candidates per row */
#define MSTR 65                /* merge scratch row stride */
#define RS_BLOCKS 1024         /* rescore blocks (8 rows each) in mid_kernel */

typedef _Float16 half8 __attribute__((ext_vector_type(8)));
typedef __attribute__((ext_vector_type(4))) float f32x4;
typedef unsigned short ushort_t;
typedef unsigned int uint_t;

// ---------------------------------------------------------------- prep: fp32->fp16 + rowwise sumsq
__global__ void prep_kernel(const float* __restrict__ X, _Float16* __restrict__ Xh,
                            float* __restrict__ sq) {
    const int tid = threadIdx.x;
    const int row = blockIdx.x * 16 + (tid >> 4);
    const int c8 = (tid & 15) * 8;
    const float4* p = (const float4*)(X + row * D_DIM + c8);
    const float4 a = p[0], b = p[1];
    half8 o;
    o[0] = (_Float16)a.x; o[1] = (_Float16)a.y; o[2] = (_Float16)a.z; o[3] = (_Float16)a.w;
    o[4] = (_Float16)b.x; o[5] = (_Float16)b.y; o[6] = (_Float16)b.z; o[7] = (_Float16)b.w;
    *(half8*)(Xh + row * D_DIM + c8) = o;
    float s = a.x * a.x + a.y * a.y + a.z * a.z + a.w * a.w
            + b.x * b.x + b.y * b.y + b.z * b.z + b.w * b.w;
    s += __shfl_xor(s, 1); s += __shfl_xor(s, 2);
    s += __shfl_xor(s, 4); s += __shfl_xor(s, 8);
    if ((tid & 15) == 0) sq[row] = s;
}

// ---------------------------------------------------------------- MFMA fp16 scores, barrier-free
// fp16 keys are CANDIDATE-RECALL ONLY; final ordering is re-derived in fp32 by mid_kernel
// with the exact accumulation order validated in rounds 1/4/6.
// Keys carry a 6-bit stream-local index in the low mantissa bits (<=64ulp perturbation,
// recall-irrelevant) so selection is pure min/med3 with no index cndmasks.
// REGISTER BUDGET: bfrag 64 VGPR + af 16 + chains ~20 + addr ~15 => needs >=115.
// __launch_bounds__(256,2) (cap 128+) is MANDATORY — (256,4) capped at 64 VGPR and
// spilled bfrag to scratch: 64 MB WRITE_SIZE, 407 MB FETCH, 2.4x slower (round 7).
__launch_bounds__(256, 2)
__global__ void nn_kernel(const _Float16* __restrict__ Xh, const float* __restrict__ sq,
                          ushort_t* __restrict__ cand) {
    __shared__ float mk[64 * MSTR];
    __shared__ int mj[64 * MSTR];

    const int tid = threadIdx.x;
    const int w = tid >> 6;
    const int lane = tid & 63;
    const int quad = lane >> 4;
    const int l15 = lane & 15;
    const int i0 = blockIdx.x * 64;
    const int sp = blockIdx.y;
    const int j0 = sp * JSPAN;

    // B-operand frags (i side), loaded straight from global (coalesced; L2-resident)
    half8 bfrag[4][4];
#pragma unroll
    for (int n = 0; n < 4; ++n)
#pragma unroll
        for (int k = 0; k < 4; ++k)
            bfrag[n][k] = *(const half8*)(Xh + (i0 + n * 16 + l15) * D_DIM + k * 32 + quad * 8);

    float c0[4], c1[4], c2[4], c3[4], sk[4];
#pragma unroll
    for (int n = 0; n < 4; ++n) { c0[n] = c1[n] = c2[n] = c3[n] = sk[n] = 1e30f; }

    int icol[4];
#pragma unroll
    for (int n = 0; n < 4; ++n) icol[n] = i0 + n * 16 + l15;

    const bool blk_excl = (sp == (i0 / JSPAN));
    const int excl_jt = (i0 & (JSPAN - 1)) >> 6;

    for (int jt = 0; jt < NJT; ++jt) {
        const int jbase = j0 + jt * 64;
        const int jrow = jbase + w * 16 + l15;
        half8 af[4];
#pragma unroll
        for (int k = 0; k < 4; ++k)
            af[k] = *(const half8*)(Xh + jrow * D_DIM + k * 32 + quad * 8);
        const f32x4 sq4 = *(const f32x4*)(sq + jbase + w * 16 + quad * 4);
        const int jg = jbase + w * 16 + quad * 4;  // + r
        const bool excl = blk_excl && (jt == excl_jt);
        const uint_t ib = (uint_t)(jt * 4);

#pragma unroll
        for (int n = 0; n < 4; ++n) {
            f32x4 acc = {0.f, 0.f, 0.f, 0.f};
#pragma unroll
            for (int k = 0; k < 4; ++k)
                acc = __builtin_amdgcn_mfma_f32_16x16x32_f16(af[k], bfrag[n][k], acc, 0, 0, 0);
            float q0 = fmaf(-2.f, acc[0], sq4[0]);
            float q1 = fmaf(-2.f, acc[1], sq4[1]);
            float q2 = fmaf(-2.f, acc[2], sq4[2]);
            float q3 = fmaf(-2.f, acc[3], sq4[3]);
            if (excl) {  // wave-uniform branch; self-exclusion BEFORE packing/selection
                if (jg + 0 == icol[n]) q0 = 1e30f;
                if (jg + 1 == icol[n]) q1 = 1e30f;
                if (jg + 2 == icol[n]) q2 = 1e30f;
                if (jg + 3 == icol[n]) q3 = 1e30f;
            }
            const float p0 = __uint_as_float((__float_as_uint(q0) & 0xFFFFFFC0u) | (ib + 0));
            const float p1 = __uint_as_float((__float_as_uint(q1) & 0xFFFFFFC0u) | (ib + 1));
            const float p2 = __uint_as_float((__float_as_uint(q2) & 0xFFFFFFC0u) | (ib + 2));
            const float p3 = __uint_as_float((__float_as_uint(q3) & 0xFFFFFFC0u) | (ib + 3));
            // quad top-2 via pure min/max network (indices ride in the low bits)
            const float min01 = fminf(p0, p1), max01 = fmaxf(p0, p1);
            const float min23 = fminf(p2, p3), max23 = fmaxf(p2, p3);
            const float kmin = fminf(min01, min23);
            const float ksec = fminf(fmaxf(min01, min23), fminf(max01, max23));
            // quad-min -> sorted top-4 chain (med3)
            c3[n] = __builtin_amdgcn_fmed3f(c2[n], c3[n], kmin);
            c2[n] = __builtin_amdgcn_fmed3f(c1[n], c2[n], kmin);
            c1[n] = __builtin_amdgcn_fmed3f(c0[n], c1[n], kmin);
            c0[n] = fminf(c0[n], kmin);
            // quad-second -> side top-1
            sk[n] = fminf(sk[n], ksec);
        }
    }

    // fold side value into each chain (once per stream per n)
#pragma unroll
    for (int n = 0; n < 4; ++n) {
        const float v = sk[n];
        c3[n] = __builtin_amdgcn_fmed3f(c2[n], c3[n], v);
        c2[n] = __builtin_amdgcn_fmed3f(c1[n], c2[n], v);
        c1[n] = __builtin_amdgcn_fmed3f(c0[n], c1[n], v);
        c0[n] = fminf(c0[n], v);
    }

    // decode + write: 16 streams x top-4 -> merge scratch
    const int s = w * 4 + quad;
    const int jdec0 = j0 + w * 16 + quad * 4;  // + (p>>2)*64 + (p&3)
#pragma unroll
    for (int n = 0; n < 4; ++n) {
        const int il = n * 16 + l15;
        const int base = il * MSTR + s * 4;
        float cc[4] = {c0[n], c1[n], c2[n], c3[n]};
#pragma unroll
        for (int e = 0; e < 4; ++e) {
            const uint_t p = __float_as_uint(cc[e]) & 63u;
            mk[base + e] = cc[e];
            mj[base + e] = jdec0 + (int)(p >> 2) * 64 + (int)(p & 3);
        }
    }
    __syncthreads();
    if (tid < 64) {
        float a0 = 1e30f, a1 = 1e30f, a2 = 1e30f, a3 = 1e30f;
        int b0 = 0, b1 = 0, b2 = 0, b3 = 0;
        for (int e = 0; e < 64; ++e) {
            float k = mk[tid * MSTR + e];
            int j = mj[tid * MSTR + e];
            bool l0 = k < a0, l1 = k < a1, l2 = k < a2, l3 = k < a3;
            a3 = l2 ? a2 : (l3 ? k : a3); b3 = l2 ? b2 : (l3 ? j : b3);
            a2 = l1 ? a1 : (l2 ? k : a2); b2 = l1 ? b1 : (l2 ? j : b2);
            a1 = l0 ? a0 : (l1 ? k : a1); b1 = l0 ? b0 : (l1 ? j : b1);
            a0 = l0 ? k : a0;             b0 = l0 ? j : b0;
        }
        const int gi = i0 + tid;
        ushort_t* c = cand + (sp * T_PTS + gi) * 4;
        c[0] = (ushort_t)b0; c[1] = (ushort_t)b1; c[2] = (ushort_t)b2; c[3] = (ushort_t)b3;
    }
}

// ---------------------------------------------------------------- mid: rescore (R4/R6-verbatim arithmetic) + Y=XW+b
// CRITICAL: the rescore dot MUST stay a per-thread sequential fma chain
// (`ssum += a.x*b2.x;` x4, loop over q) — this accumulation order matched the
// reference in rounds 1/4/6. Any re-association flips marginal neighbor pairs.
__global__ void mid_kernel(const float* __restrict__ X, const float* __restrict__ sq,
                           const ushort_t* __restrict__ cand, int* __restrict__ nbrs,
                           const float* __restrict__ W, const float* __restrict__ b,
                           float* __restrict__ Y, float* __restrict__ out) {
    __shared__ float keys[8][NC];
    __shared__ int idxs[8][NC];
    __shared__ float Xs[16 * LSTR];
    __shared__ float Ws[D_DIM * C_OUT];
    const int tid = threadIdx.x;

    if (blockIdx.x < RS_BLOCKS) {
        // exact fp32 rescore of 32 candidates: 8 rows/block, 1 thread per (row, candidate)
        const int t = tid & 31;
        const int ii = tid >> 5;  // 0..7
        const int i = blockIdx.x * 8 + ii;
        {
            const int spc = t >> 2, c = t & 3;
            const int j = (int)cand[(spc * T_PTS + i) * 4 + c];
            const float4* xi = (const float4*)(X + i * D_DIM);
            const float4* xj = (const float4*)(X + j * D_DIM);
            float ssum = 0.f;
#pragma unroll
            for (int q = 0; q < 32; ++q) {
                float4 a = xi[q], b2 = xj[q];
                ssum += a.x * b2.x; ssum += a.y * b2.y; ssum += a.z * b2.z; ssum += a.w * b2.w;
            }
            float key = sq[j] - 2.f * ssum;
            if (j == i) key = 1e30f;
            keys[ii][t] = key;
            idxs[ii][t] = j;
        }
        __syncthreads();
        if (t == 0) {
            float m0 = 1e30f, m1 = 1e30f;
            int n0 = 0x7fffffff, n1 = 0x7fffffff;
            for (int e = 0; e < NC; ++e) {
                float k = keys[ii][e];
                int j = idxs[ii][e];
                bool lt0 = (k < m0) || (k == m0 && j < n0);
                bool lt1 = (k < m1) || (k == m1 && j < n1);
                if (lt0) { m1 = m0; n1 = n0; m0 = k; n0 = j; }
                else if (lt1) { m1 = k; n1 = j; }
            }
            nbrs[i * 2 + 0] = n0;
            nbrs[i * 2 + 1] = n1;
        }
    } else {
        // Y = X@W + b, plus logits rows [0,T)
        const int r0 = (blockIdx.x - RS_BLOCKS) * 16;
        const float4* src = (const float4*)(X + r0 * D_DIM);
#pragma unroll
        for (int it = 0; it < 2; ++it) {
            int f = tid + it * 256;  // 0..511
            int row = f >> 5, kq = f & 31;
            *(float4*)(Xs + row * LSTR + kq * 4) = src[row * 32 + kq];
        }
#pragma unroll
        for (int it = 0; it < 2; ++it) {
            int f = tid + it * 256;
            ((float4*)Ws)[f] = ((const float4*)W)[f];
        }
        __syncthreads();
        const int r = tid >> 4, c = tid & 15;
        float s = b[c];
#pragma unroll
        for (int d = 0; d < D_DIM; ++d) s += Xs[r * LSTR + d] * Ws[d * C_OUT + c];
        const int row = r0 + r;
        Y[row * C_OUT + c] = s;
        out[row * C_OUT + c] = s;
    }
}

// ---------------------------------------------------------------- synthetic rows: lerp of Y
__global__ void syn_kernel(const float* __restrict__ Y, const int* __restrict__ nbrs,
                           const int* __restrict__ nn_idx, const float* __restrict__ gaps,
                           float* __restrict__ out) {
    const int idx = blockIdx.x * 256 + threadIdx.x;
    const int m = idx >> 4;
    const int c = idx & 15;
    const int src = m >> 2;       // repeat(arange(T), 4)
    const int sel = nn_idx[m];    // 0 or 1
    const int ch = nbrs[src * 2 + sel];
    const float g = gaps[m];
    const float ys = Y[src * C_OUT + c];
    const float yc = Y[ch * C_OUT + c];
    out[(T_PTS + m) * C_OUT + c] = ys + g * (yc - ys);
}

extern "C" void kernel_launch(void* const* d_in, const int* in_sizes, int n_in,
                              void* d_out, int out_size, void* d_ws, size_t ws_size,
                              hipStream_t stream) {
    const float* X = (const float*)d_in[0];
    const int* nn_idx = (const int*)d_in[1];
    const float* gaps = (const float*)d_in[2];
    const float* W = (const float*)d_in[3];
    const float* b = (const float*)d_in[4];
    float* out = (float*)d_out;

    char* ws = (char*)d_ws;
    _Float16* Xh = (_Float16*)ws;                                  // 2 MB
    float* sq = (float*)(ws + 2097152);                            // 32 KB
    ushort_t* cand = (ushort_t*)(ws + 2097152 + 32768);            // 512 KB
    int* nbrs = (int*)(ws + 2097152 + 32768 + 524288);             // 64 KB
    float* Y = (float*)(ws + 2097152 + 32768 + 524288 + 65536);    // 512 KB

    prep_kernel<<<T_PTS / 16, 256, 0, stream>>>(X, Xh, sq);
    nn_kernel<<<dim3(T_PTS / 64, NSPLIT), 256, 0, stream>>>(Xh, sq, cand);
    mid_kernel<<<RS_BLOCKS + T_PTS / 16, 256, 0, stream>>>(X, sq, cand, nbrs, W, b, Y, out);
    syn_kernel<<<(4 * T_PTS * C_OUT) / 256, 256, 0, stream>>>(Y, nbrs, nn_idx, gaps, out);
}